// Round 15
// baseline (406.405 us; speedup 1.0000x reference)
//
#include <hip/hip_runtime.h>
#include <stdint.h>

#define Nn   50000
#define Ee   800000
#define Dd   128
#define Gg   512
#define NHIDc 512
#define NOUTc 768
#define EPSf 1e-5f
#define CAP  64          // bucket capacity per node (Poisson(17), max deg ~46)
#define PRNG 6250        // node-range per XCD partition (Nn/8)
#define NBPART 12500     // agg blocks (block per 4 nodes) = #stat-partials
#define NBRED  250       // bn reduce blocks (50 rows each)

// ---- workspace byte offsets ----
#define OFF_CNT    0ul            // N int (degree incl self-loop)
#define OFF_ES     200192ul       // N float
#define OFF_ED     400384ul       // N float
#define OFF_STATS  600576ul       // 256 float
#define OFF_POOLED 601600ul       // G*D float
#define OFF_M1     863744ul       // 512*512 float (first 257 floats double as statsAcc+ticket)
#define OFF_M2     1912320ul      // 512*512 float
#define OFF_COL    2960896ul      // N*64 int  (padded buckets)
#define OFF_H      15760896ul     // N*64 u32  (packed bf16x2)
#define OFF_AGG    28560896ul     // N*64 u32  (packed bf16x2)
#define OFF_XCUR   41360896ul     // N*64 u32  (packed bf16x2 residual stream)
#define OFF_PART   54160896ul     // NBPART*256 float = 12.8 MB stats partials
#define OFF_XBF    66960896ul     // N*64 u32  (packed bf16x2 input x)

#define BF_LO(u) __uint_as_float((u) << 16)
#define BF_HI(u) __uint_as_float((u) & 0xffff0000u)

typedef __attribute__((ext_vector_type(8))) short bf16x8;
typedef __attribute__((ext_vector_type(4))) float f32x4;

__device__ inline uint32_t bfpack(float x, float y) {
    uint32_t ux = __float_as_uint(x), uy = __float_as_uint(y);
    ux += 0x7fff + ((ux >> 16) & 1);   // RNE
    uy += 0x7fff + ((uy >> 16) & 1);
    return (ux >> 16) | (uy & 0xffff0000u);
}
__device__ inline short bf1(float x) {
    uint32_t u = __float_as_uint(x);
    u += 0x7fff + ((u >> 16) & 1);
    return (short)(u >> 16);
}
__device__ inline float wred16(float v) {
    v += __shfl_xor(v, 1); v += __shfl_xor(v, 2);
    v += __shfl_xor(v, 4); v += __shfl_xor(v, 8);
    return v;
}

// ---------------- prep: x->bf16 pack, bucket init, stats accumulator zero ----------------
__global__ void k_prep(const float* __restrict__ x, uint32_t* __restrict__ xbf,
                       int* cnt, int* colx, float* statsAcc, int* ticket) {
    int i = blockIdx.x * 256 + threadIdx.x;   // 800000 threads = Nn*16 exactly
    {
        float4 a = reinterpret_cast<const float4*>(x)[2 * i];
        float4 b = reinterpret_cast<const float4*>(x)[2 * i + 1];
        uint32_t o[4] = {bfpack(a.x, a.y), bfpack(a.z, a.w),
                         bfpack(b.x, b.y), bfpack(b.z, b.w)};
        reinterpret_cast<uint4*>(xbf)[i] = *reinterpret_cast<uint4*>(o);
    }
    if (i < Nn) {
        cnt[i] = 1;                        // self-loop occupies slot 0
        colx[(size_t)i * CAP] = i;
    }
    if (i < 256) statsAcc[i] = 0.f;
    if (i == 256) *ticket = 0;
}

// XCD-partitioned fill: group g (blockIdx&7) handles dst in [g*PRNG,(g+1)*PRNG)
__global__ void k_bucket_fill(const int* __restrict__ ei, int* cnt, int* colx) {
    int grp = blockIdx.x & 7;
    int e = (blockIdx.x >> 3) * 256 + threadIdx.x;
    if (e >= Ee) return;
    int d = ei[Ee + e];
    if (d / PRNG != grp) return;
    int s = ei[e];
    int pos = atomicAdd(&cnt[d], 1);
    if (pos < CAP) colx[(size_t)d * CAP + pos] = s;
}

// ---------------- fused BN-apply + node GEMM (MFMA bf16) + optional GAT scores ----------------
#define WTP 136   // padded k-stride (bf16 elems); WTP/2 = 68 u32
__global__ __launch_bounds__(512) void k_gemm_fused(
        const uint32_t* __restrict__ XP, const uint32_t* __restrict__ AggP,
        const float* __restrict__ stats, const float* __restrict__ W,
        const int* __restrict__ cntP,
        uint32_t* __restrict__ Hout, uint32_t* __restrict__ XoutP,
        const float* __restrict__ a_src, const float* __restrict__ a_dst,
        float* __restrict__ esO, float* __restrict__ edO) {
    __shared__ short WT[128 * WTP];     // 34816 B : W^T bf16, WT[c*WTP+k]
    __shared__ short XT[8][16 * WTP];   // 34816 B : per-wave xnew slab (then H slab)
    __shared__ float isqL[128];

    int t = threadIdx.x;
    for (int i = t; i < 128 * 128; i += 512) {
        int k = i >> 7, c = i & 127;
        WT[c * WTP + k] = bf1(W[i]);
    }
    __syncthreads();

    int wave = t >> 6, lane = t & 63;
    int arow = lane & 15, kg = lane >> 4;
    int c4 = (lane * 4) & 63;           // phase-1: this lane's 4 u32 cols (8 features)
    int prow = lane >> 4;               // phase-1: row offset within 4-row group
    float scv[8], shv[8];
    if (stats) {
        #pragma unroll
        for (int j = 0; j < 8; ++j) {
            scv[j] = stats[2 * c4 + j];
            shv[j] = stats[128 + 2 * c4 + j];
        }
    }
    float asr[8], adr[8];
    if (esO) {
        #pragma unroll
        for (int jj = 0; jj < 8; ++jj) {
            asr[jj] = a_src[(lane & 15) * 8 + jj];
            adr[jj] = a_dst[(lane & 15) * 8 + jj];
        }
    }

    for (int tile = blockIdx.x * 128; tile < Nn; tile += gridDim.x * 128) {
        int rbase = tile + wave * 16;
        if (lane < 16) {
            int rg = rbase + lane;
            isqL[wave * 16 + lane] = (cntP && rg < Nn) ? rsqrtf((float)cntP[rg]) : 1.f;
        }
        // ---- phase 1: 4x uint4 coalesced loads -> BN+ReLU+residual -> bf16 slab ----
        uint32_t* xtw = reinterpret_cast<uint32_t*>(XT[wave]);
        #pragma unroll
        for (int b = 0; b < 4; ++b) {
            int row = b * 4 + prow;
            int rg = rbase + row;
            uint32_t xv[4] = {0u, 0u, 0u, 0u};
            if (rg < Nn) {
                *reinterpret_cast<uint4*>(xv) =
                    *reinterpret_cast<const uint4*>(&XP[(size_t)rg * 64 + c4]);
                if (AggP) {
                    uint32_t av[4];
                    *reinterpret_cast<uint4*>(av) =
                        *reinterpret_cast<const uint4*>(&AggP[(size_t)rg * 64 + c4]);
                    #pragma unroll
                    for (int q = 0; q < 4; ++q) {
                        float n0 = fmaxf(BF_LO(av[q]) * scv[2 * q] + shv[2 * q], 0.f) + BF_LO(xv[q]);
                        float n1 = fmaxf(BF_HI(av[q]) * scv[2 * q + 1] + shv[2 * q + 1], 0.f) + BF_HI(xv[q]);
                        xv[q] = bfpack(n0, n1);
                    }
                    *reinterpret_cast<uint4*>(&XoutP[(size_t)rg * 64 + c4]) =
                        *reinterpret_cast<uint4*>(xv);
                }
            }
            *reinterpret_cast<uint4*>(&xtw[row * (WTP / 2) + c4]) = *reinterpret_cast<uint4*>(xv);
        }
        // ---- phase 2: MFMA ----
        bf16x8 afr[4];
        #pragma unroll
        for (int kt = 0; kt < 4; ++kt)
            afr[kt] = *reinterpret_cast<bf16x8*>(&XT[wave][arow * WTP + kt * 32 + kg * 8]);
        float sR[4];
        #pragma unroll
        for (int rr = 0; rr < 4; ++rr) sR[rr] = isqL[wave * 16 + kg * 4 + rr];

        #pragma unroll
        for (int ct = 0; ct < 8; ++ct) {
            int c = ct * 16 + arow;
            f32x4 acc = {0.f, 0.f, 0.f, 0.f};
            #pragma unroll
            for (int kt = 0; kt < 4; ++kt) {
                bf16x8 b = *reinterpret_cast<bf16x8*>(&WT[c * WTP + kt * 32 + kg * 8]);
                acc = __builtin_amdgcn_mfma_f32_16x16x32_bf16(afr[kt], b, acc, 0, 0, 0);
            }
            #pragma unroll
            for (int rr = 0; rr < 4; ++rr)
                XT[wave][(kg * 4 + rr) * WTP + c] = bf1(acc[rr] * sR[rr]);
        }
        // ---- phase 3: coalesced copy-out + optional GAT scores ----
        #pragma unroll
        for (int p = 0; p < 4; ++p) {
            int rsl = p * 4 + kg;
            int rg = rbase + rsl;
            if (rg < Nn) {
                int chunk = lane & 15;
                bf16x8 vv = *reinterpret_cast<bf16x8*>(&XT[wave][rsl * WTP + chunk * 8]);
                *reinterpret_cast<bf16x8*>(reinterpret_cast<short*>(Hout) + (size_t)rg * 128 + chunk * 8) = vv;
                if (esO) {
                    float dsum = 0.f, ddum = 0.f;
                    #pragma unroll
                    for (int jj = 0; jj < 8; ++jj) {
                        float hv = __uint_as_float(((uint32_t)(unsigned short)vv[jj]) << 16);
                        dsum += hv * asr[jj];
                        ddum += hv * adr[jj];
                    }
                    dsum = wred16(dsum); ddum = wred16(ddum);
                    if ((lane & 15) == 0) { esO[rg] = dsum; edO[rg] = ddum; }
                }
            }
        }
    }
}

// ---------------- GCN aggregation + fused BN-stats partials ----------------
__global__ __launch_bounds__(256) void k_gcn_agg(const uint32_t* __restrict__ H,
                                                 const int* __restrict__ cnt,
                                                 const int* __restrict__ colx,
                                                 uint32_t* __restrict__ aggP,
                                                 float* __restrict__ part) {
    int wave = threadIdx.x >> 6, lane = threadIdx.x & 63;
    int half = lane >> 5, fl = lane & 31;
    int nid = blockIdx.x * 4 + wave;
    const uint2* H2 = reinterpret_cast<const uint2*>(H);

    int degF = cnt[nid];
    int deg = degF > CAP ? CAP : degF;
    size_t cb = (size_t)nid * CAP;
    int m = (deg - half + 1) >> 1;
    float f0a = 0.f, f1a = 0.f, f2a = 0.f, f3a = 0.f;
    float f0b = 0.f, f1b = 0.f, f2b = 0.f, f3b = 0.f;
    float f0c = 0.f, f1c = 0.f, f2c = 0.f, f3c = 0.f;
    float f0d = 0.f, f1d = 0.f, f2d = 0.f, f3d = 0.f;
    int k = 0;
    for (; k + 3 < m; k += 4) {
        int s0 = colx[cb + half + 2 * k];
        int s1 = colx[cb + half + 2 * k + 2];
        int s2 = colx[cb + half + 2 * k + 4];
        int s3 = colx[cb + half + 2 * k + 6];
        uint2 u0 = H2[(size_t)s0 * 32 + fl];
        uint2 u1 = H2[(size_t)s1 * 32 + fl];
        uint2 u2 = H2[(size_t)s2 * 32 + fl];
        uint2 u3 = H2[(size_t)s3 * 32 + fl];
        f0a += BF_LO(u0.x); f1a += BF_HI(u0.x); f2a += BF_LO(u0.y); f3a += BF_HI(u0.y);
        f0b += BF_LO(u1.x); f1b += BF_HI(u1.x); f2b += BF_LO(u1.y); f3b += BF_HI(u1.y);
        f0c += BF_LO(u2.x); f1c += BF_HI(u2.x); f2c += BF_LO(u2.y); f3c += BF_HI(u2.y);
        f0d += BF_LO(u3.x); f1d += BF_HI(u3.x); f2d += BF_LO(u3.y); f3d += BF_HI(u3.y);
    }
    for (; k < m; ++k) {
        int s0 = colx[cb + half + 2 * k];
        uint2 u0 = H2[(size_t)s0 * 32 + fl];
        f0a += BF_LO(u0.x); f1a += BF_HI(u0.x); f2a += BF_LO(u0.y); f3a += BF_HI(u0.y);
    }
    float f0 = (f0a + f0b) + (f0c + f0d);
    float f1 = (f1a + f1b) + (f1c + f1d);
    float f2 = (f2a + f2b) + (f2c + f2d);
    float f3 = (f3a + f3b) + (f3c + f3d);
    f0 += __shfl_xor(f0, 32); f1 += __shfl_xor(f1, 32);
    f2 += __shfl_xor(f2, 32); f3 += __shfl_xor(f3, 32);

    float o0 = 0.f, o1 = 0.f, o2 = 0.f, o3 = 0.f;
    if (half == 0) {
        float wd = rsqrtf((float)degF);
        o0 = f0 * wd; o1 = f1 * wd; o2 = f2 * wd; o3 = f3 * wd;
        uint2 o;
        o.x = bfpack(o0, o1);
        o.y = bfpack(o2, o3);
        reinterpret_cast<uint2*>(aggP)[(size_t)nid * 32 + fl] = o;
    }
    __shared__ float SS[4][128];
    __shared__ float QQ[4][128];
    if (half == 0) {
        SS[wave][4 * fl + 0] = o0; QQ[wave][4 * fl + 0] = o0 * o0;
        SS[wave][4 * fl + 1] = o1; QQ[wave][4 * fl + 1] = o1 * o1;
        SS[wave][4 * fl + 2] = o2; QQ[wave][4 * fl + 2] = o2 * o2;
        SS[wave][4 * fl + 3] = o3; QQ[wave][4 * fl + 3] = o3 * o3;
    }
    __syncthreads();
    int t = threadIdx.x;
    if (t < 128) {
        part[blockIdx.x * 256 + t]       = (SS[0][t] + SS[1][t]) + (SS[2][t] + SS[3][t]);
        part[blockIdx.x * 256 + 128 + t] = (QQ[0][t] + QQ[1][t]) + (QQ[2][t] + QQ[3][t]);
    }
}

// ---------------- GAT aggregation + fused BN-stats partials ----------------
__global__ __launch_bounds__(256) void k_gat_agg(const uint32_t* __restrict__ H,
                                                 const int* __restrict__ cnt,
                                                 const int* __restrict__ colx,
                                                 const float* __restrict__ es,
                                                 const float* __restrict__ ed,
                                                 uint32_t* __restrict__ aggP,
                                                 float* __restrict__ part) {
    int wave = threadIdx.x >> 6, lane = threadIdx.x & 63;
    int half = lane >> 5, fl = lane & 31;
    int nid = blockIdx.x * 4 + wave;
    const uint2* H2 = reinterpret_cast<const uint2*>(H);

    int degF = cnt[nid];
    int deg = degF > CAP ? CAP : degF;
    size_t cb = (size_t)nid * CAP;
    float edd = ed[nid];
    int m = (deg - half + 1) >> 1;
    float f0a = 0.f, f1a = 0.f, f2a = 0.f, f3a = 0.f, dena = 0.f;
    float f0b = 0.f, f1b = 0.f, f2b = 0.f, f3b = 0.f, denb = 0.f;
    float f0c = 0.f, f1c = 0.f, f2c = 0.f, f3c = 0.f, denc = 0.f;
    float f0d = 0.f, f1d = 0.f, f2d = 0.f, f3d = 0.f, dend = 0.f;
    int k = 0;
    for (; k + 3 < m; k += 4) {
        int s0 = colx[cb + half + 2 * k];
        int s1 = colx[cb + half + 2 * k + 2];
        int s2 = colx[cb + half + 2 * k + 4];
        int s3 = colx[cb + half + 2 * k + 6];
        float e0 = es[s0] + edd, e1 = es[s1] + edd;
        float e2 = es[s2] + edd, e3 = es[s3] + edd;
        e0 = (e0 < 0.f) ? 0.2f * e0 : e0;
        e1 = (e1 < 0.f) ? 0.2f * e1 : e1;
        e2 = (e2 < 0.f) ? 0.2f * e2 : e2;
        e3 = (e3 < 0.f) ? 0.2f * e3 : e3;
        float w0 = __expf(e0), w1 = __expf(e1), w2 = __expf(e2), w3 = __expf(e3);
        uint2 u0 = H2[(size_t)s0 * 32 + fl];
        uint2 u1 = H2[(size_t)s1 * 32 + fl];
        uint2 u2 = H2[(size_t)s2 * 32 + fl];
        uint2 u3 = H2[(size_t)s3 * 32 + fl];
        f0a += w0 * BF_LO(u0.x); f1a += w0 * BF_HI(u0.x);
        f2a += w0 * BF_LO(u0.y); f3a += w0 * BF_HI(u0.y); dena += w0;
        f0b += w1 * BF_LO(u1.x); f1b += w1 * BF_HI(u1.x);
        f2b += w1 * BF_LO(u1.y); f3b += w1 * BF_HI(u1.y); denb += w1;
        f0c += w2 * BF_LO(u2.x); f1c += w2 * BF_HI(u2.x);
        f2c += w2 * BF_LO(u2.y); f3c += w2 * BF_HI(u2.y); denc += w2;
        f0d += w3 * BF_LO(u3.x); f1d += w3 * BF_HI(u3.x);
        f2d += w3 * BF_LO(u3.y); f3d += w3 * BF_HI(u3.y); dend += w3;
    }
    for (; k < m; ++k) {
        int s0 = colx[cb + half + 2 * k];
        float e0 = es[s0] + edd;
        e0 = (e0 < 0.f) ? 0.2f * e0 : e0;
        float w0 = __expf(e0);
        uint2 u0 = H2[(size_t)s0 * 32 + fl];
        f0a += w0 * BF_LO(u0.x); f1a += w0 * BF_HI(u0.x);
        f2a += w0 * BF_LO(u0.y); f3a += w0 * BF_HI(u0.y); dena += w0;
    }
    float f0 = (f0a + f0b) + (f0c + f0d);
    float f1 = (f1a + f1b) + (f1c + f1d);
    float f2 = (f2a + f2b) + (f2c + f2d);
    float f3 = (f3a + f3b) + (f3c + f3d);
    float den = (dena + denb) + (denc + dend);
    f0 += __shfl_xor(f0, 32); f1 += __shfl_xor(f1, 32);
    f2 += __shfl_xor(f2, 32); f3 += __shfl_xor(f3, 32);
    den += __shfl_xor(den, 32);

    float o0 = 0.f, o1 = 0.f, o2 = 0.f, o3 = 0.f;
    if (half == 0) {
        float inv = 1.f / den;
        o0 = f0 * inv; o1 = f1 * inv; o2 = f2 * inv; o3 = f3 * inv;
        uint2 o;
        o.x = bfpack(o0, o1);
        o.y = bfpack(o2, o3);
        reinterpret_cast<uint2*>(aggP)[(size_t)nid * 32 + fl] = o;
    }
    __shared__ float SS[4][128];
    __shared__ float QQ[4][128];
    if (half == 0) {
        SS[wave][4 * fl + 0] = o0; QQ[wave][4 * fl + 0] = o0 * o0;
        SS[wave][4 * fl + 1] = o1; QQ[wave][4 * fl + 1] = o1 * o1;
        SS[wave][4 * fl + 2] = o2; QQ[wave][4 * fl + 2] = o2 * o2;
        SS[wave][4 * fl + 3] = o3; QQ[wave][4 * fl + 3] = o3 * o3;
    }
    __syncthreads();
    int t = threadIdx.x;
    if (t < 128) {
        part[blockIdx.x * 256 + t]       = (SS[0][t] + SS[1][t]) + (SS[2][t] + SS[3][t]);
        part[blockIdx.x * 256 + 128 + t] = (QQ[0][t] + QQ[1][t]) + (QQ[2][t] + QQ[3][t]);
    }
}

// ---------------- BN reduce + finalize (single kernel, ticketed last-block) ----------------
// Each block coalesced-sums 50 partial rows, atomically accumulates into statsAcc;
// the last-arriving block computes scale/shift and self-resets statsAcc/ticket
// (self-reset => deterministic and rocprof-replay-safe).
__global__ __launch_bounds__(256) void k_bn_redfin(const float* __restrict__ part,
                                                   float* statsAcc, int* ticket,
                                                   float* stats,
                                                   const float* __restrict__ gamma,
                                                   const float* __restrict__ beta) {
    int t = threadIdx.x;
    int r0 = blockIdx.x * 50;
    float acc = 0.f;
    #pragma unroll 5
    for (int r = r0; r < r0 + 50; ++r) acc += part[(size_t)r * 256 + t];
    atomicAdd(&statsAcc[t], acc);
    __threadfence();
    __syncthreads();
    __shared__ int amLast;
    if (t == 0) amLast = (atomicAdd(ticket, 1) == NBRED - 1) ? 1 : 0;
    __syncthreads();
    if (amLast) {
        float S = 0.f, Q = 0.f;
        if (t < 128) {
            S = atomicAdd(&statsAcc[t], 0.f);        // coherent read across XCDs
            Q = atomicAdd(&statsAcc[128 + t], 0.f);
        }
        __syncthreads();
        atomicExch(&statsAcc[t], 0.f);               // self-reset
        if (t == 0) atomicExch(ticket, 0);
        if (t < 128) {
            const float invN = 1.f / (float)Nn;
            float mean = S * invN;
            float var = Q * invN - mean * mean;
            float scv = rsqrtf(var + EPSf) * gamma[t];
            stats[t] = scv;
            stats[128 + t] = beta[t] - mean * scv;
        }
    }
}

// ---------------- mean pool, fused with final BN-apply (packed inputs) ----------------
__global__ __launch_bounds__(256) void k_pool(const uint32_t* __restrict__ AP,
                                              const float* __restrict__ stats,
                                              const uint32_t* __restrict__ XcP,
                                              const int* __restrict__ batch,
                                              float* __restrict__ pooled) {
    int g = blockIdx.x;
    int lo = 0, hi = Nn;
    while (lo < hi) { int mid = (lo + hi) >> 1; if (batch[mid] < g) lo = mid + 1; else hi = mid; }
    int start = lo;
    lo = start; hi = Nn;
    while (lo < hi) { int mid = (lo + hi) >> 1; if (batch[mid] < g + 1) lo = mid + 1; else hi = mid; }
    int end = lo;

    int f = threadIdx.x & 127, rg = threadIdx.x >> 7;
    float sc = stats[f], sh = stats[128 + f];
    float s = 0.f;
    for (int r = start + rg; r < end; r += 2) {
        uint32_t u = AP[(size_t)r * 64 + (f >> 1)];
        uint32_t ux = XcP[(size_t)r * 64 + (f >> 1)];
        float a  = (f & 1) ? BF_HI(u)  : BF_LO(u);
        float xv = (f & 1) ? BF_HI(ux) : BF_LO(ux);
        s += fmaxf(a * sc + sh, 0.f) + xv;
    }
    __shared__ float red[256];
    red[threadIdx.x] = s; __syncthreads();
    if (threadIdx.x < 128) {
        float tot = red[threadIdx.x] + red[threadIdx.x + 128];
        float cntg = (float)(end - start);
        pooled[g * Dd + threadIdx.x] = (cntg > 0.f) ? tot / cntg : 0.f;
    }
}

// ---------------- MLP GEMM: MFMA bf16, 64x64 tile per 256-thr block ----------------
// A[M,K] fp32, B[K,N] fp32 (row-major), fp32 accum; M,N,K multiples of 64
#define ASTR 80   // padded k-stride (shorts) for LDS tiles
__global__ __launch_bounds__(256) void k_mlp_mfma(const float* __restrict__ A,
                                                  const float* __restrict__ B,
                                                  const float* __restrict__ bias,
                                                  float* __restrict__ C,
                                                  int M, int K, int Nc, int do_relu) {
    __shared__ short As[64 * ASTR];   // As[r*ASTR + k]
    __shared__ short Bs[64 * ASTR];   // Bs[n*ASTR + k]

    int nbx = Nc >> 6;
    int by = blockIdx.x / nbx, bx = blockIdx.x - by * nbx;
    int r0 = by * 64, n0 = bx * 64;
    int t = threadIdx.x;
    int wave = t >> 6, lane = t & 63;
    int arow = lane & 15, kg = lane >> 4;
    int sr = t >> 2, sc = (t & 3) * 16;   // staging: 4 threads per row/k-row

    f32x4 acc0 = {0, 0, 0, 0}, acc1 = {0, 0, 0, 0};
    f32x4 acc2 = {0, 0, 0, 0}, acc3 = {0, 0, 0, 0};

    for (int kc = 0; kc < K; kc += 64) {
        // stage A[r0+sr][kc+sc..+15] -> bf16 As
        {
            const float* ap = A + (size_t)(r0 + sr) * K + kc + sc;
            float4 v0 = *reinterpret_cast<const float4*>(ap);
            float4 v1 = *reinterpret_cast<const float4*>(ap + 4);
            float4 v2 = *reinterpret_cast<const float4*>(ap + 8);
            float4 v3 = *reinterpret_cast<const float4*>(ap + 12);
            uint32_t o[8] = {bfpack(v0.x, v0.y), bfpack(v0.z, v0.w),
                             bfpack(v1.x, v1.y), bfpack(v1.z, v1.w),
                             bfpack(v2.x, v2.y), bfpack(v2.z, v2.w),
                             bfpack(v3.x, v3.y), bfpack(v3.z, v3.w)};
            *reinterpret_cast<uint4*>(&As[sr * ASTR + sc])     = *reinterpret_cast<uint4*>(&o[0]);
            *reinterpret_cast<uint4*>(&As[sr * ASTR + sc + 8]) = *reinterpret_cast<uint4*>(&o[4]);
        }
        // stage B[kc+sr][n0+sc..+15] -> Bs[n][k] (transposed scatter)
        {
            const float* bp = B + (size_t)(kc + sr) * Nc + n0 + sc;
            float4 w0 = *reinterpret_cast<const float4*>(bp);
            float4 w1 = *reinterpret_cast<const float4*>(bp + 4);
            float4 w2 = *reinterpret_cast<const float4*>(bp + 8);
            float4 w3 = *reinterpret_cast<const float4*>(bp + 12);
            float wv[16] = {w0.x, w0.y, w0.z, w0.w, w1.x, w1.y, w1.z, w1.w,
                            w2.x, w2.y, w2.z, w2.w, w3.x, w3.y, w3.z, w3.w};
            #pragma unroll
            for (int j = 0; j < 16; ++j)
                Bs[(sc + j) * ASTR + sr] = bf1(wv[j]);
        }
        __syncthreads();
        bf16x8 a0 = *reinterpret_cast<bf16x8*>(&As[(wave * 16 + arow) * ASTR + kg * 8]);
        bf16x8 a1 = *reinterpret_cast<bf16x8*>(&As[(wave * 16 + arow) * ASTR + 32 + kg * 8]);
        {
            bf16x8 b0 = *reinterpret_cast<bf16x8*>(&Bs[(0 * 16 + arow) * ASTR + kg * 8]);
            bf16x8 b1 = *reinterpret_cast<bf16x8*>(&Bs[(0 * 16 + arow) * ASTR + 32 + kg * 8]);
            acc0 = __builtin_amdgcn_mfma_f32_16x16x32_bf16(a0, b0, acc0, 0, 0, 0);
            acc0 = __builtin_amdgcn_mfma_f32_16x16x32_bf16(a1, b1, acc0, 0, 0, 0);
        }
        {
            bf16x8 b0 = *reinterpret_cast<bf16x8*>(&Bs[(1 * 16 + arow) * ASTR + kg * 8]);
            bf16x8 b1 = *reinterpret_cast<bf16x8*>(&Bs[(1 * 16 + arow) * ASTR + 32 + kg * 8]);
            acc1 = __builtin_amdgcn_mfma_f32_16x16x32_bf16(a0, b0, acc1, 0, 0, 0);
            acc1 = __builtin_amdgcn_mfma_f32_16x16x32_bf16(a1, b1, acc1, 0, 0, 0);
        }
        {
            bf16x8 b0 = *reinterpret_cast<bf16x8*>(&Bs[(2 * 16 + arow) * ASTR + kg * 8]);
            bf16x8 b1 = *reinterpret_cast<bf16x8*>(&Bs[(2 * 16 + arow) * ASTR + 32 + kg * 8]);
            acc2 = __builtin_amdgcn_mfma_f32_16x16x32_bf16(a0, b0, acc2, 0, 0, 0);
            acc2 = __builtin_amdgcn_mfma_f32_16x16x32_bf16(a1, b1, acc2, 0, 0, 0);
        }
        {
            bf16x8 b0 = *reinterpret_cast<bf16x8*>(&Bs[(3 * 16 + arow) * ASTR + kg * 8]);
            bf16x8 b1 = *reinterpret_cast<bf16x8*>(&Bs[(3 * 16 + arow) * ASTR + 32 + kg * 8]);
            acc3 = __builtin_amdgcn_mfma_f32_16x16x32_bf16(a0, b0, acc3, 0, 0, 0);
            acc3 = __builtin_amdgcn_mfma_f32_16x16x32_bf16(a1, b1, acc3, 0, 0, 0);
        }
        __syncthreads();
    }
    // epilogue: row = r0 + wave*16 + kg*4 + rr; col = n0 + ct*16 + arow
    #pragma unroll
    for (int ct = 0; ct < 4; ++ct) {
        f32x4 acc = (ct == 0) ? acc0 : (ct == 1) ? acc1 : (ct == 2) ? acc2 : acc3;
        int col = n0 + ct * 16 + arow;
        float bv = bias[col];
        #pragma unroll
        for (int rr = 0; rr < 4; ++rr) {
            int row = r0 + wave * 16 + kg * 4 + rr;
            float v = acc[rr] + bv;
            if (do_relu) v = fmaxf(v, 0.f);
            C[(size_t)row * Nc + col] = v;
        }
    }
}

extern "C" void kernel_launch(void* const* d_in, const int* in_sizes, int n_in,
                              void* d_out, int out_size, void* d_ws, size_t ws_size,
                              hipStream_t stream) {
    const float* x       = (const float*)d_in[0];
    const int*   ei      = (const int*)d_in[1];
    const int*   batch   = (const int*)d_in[2];
    const float* W1      = (const float*)d_in[3];
    const float* W2      = (const float*)d_in[5];
    const float* W3      = (const float*)d_in[7];
    const float* Wa      = (const float*)d_in[9];
    const float* a_src   = (const float*)d_in[11];
    const float* a_dst   = (const float*)d_in[12];
    const float* bn_g    = (const float*)d_in[13];
    const float* bn_b    = (const float*)d_in[14];
    const float* Wm1     = (const float*)d_in[15];
    const float* bm1     = (const float*)d_in[16];
    const float* Wm2     = (const float*)d_in[17];
    const float* bm2     = (const float*)d_in[18];
    const float* Wm3     = (const float*)d_in[19];
    const float* bm3     = (const float*)d_in[20];
    const float* Wm4     = (const float*)d_in[21];
    const float* bm4     = (const float*)d_in[22];

    char* ws = (char*)d_ws;
    int*      cnt    = (int*)(ws + OFF_CNT);
    float*    es     = (float*)(ws + OFF_ES);
    float*    ed     = (float*)(ws + OFF_ED);
    float*    stats  = (float*)(ws + OFF_STATS);
    float*    pooled = (float*)(ws + OFF_POOLED);
    float*    m1     = (float*)(ws + OFF_M1);
    float*    m2     = (float*)(ws + OFF_M2);
    int*      colx   = (int*)(ws + OFF_COL);
    uint32_t* h      = (uint32_t*)(ws + OFF_H);
    uint32_t* aggP   = (uint32_t*)(ws + OFF_AGG);
    uint32_t* xcurP  = (uint32_t*)(ws + OFF_XCUR);
    float*    part   = (float*)(ws + OFF_PART);
    uint32_t* xbf    = (uint32_t*)(ws + OFF_XBF);
    float*    statsAcc = m2;                 // 256 floats (time-disjoint from MLP use)
    int*      ticket   = (int*)(m2 + 256);

    const int nbE8  = ((Ee + 255) / 256) * 8;    // 25000 partitioned blocks
    const int nbGemm = (Nn + 127) / 128;         // 391 tiles of 128 rows (512 thr)
    const int nbPrep = (Nn * 16 + 255) / 256;    // 3125 (exact for x2bf)

    // ---- prep + bucket CSR build ----
    k_prep<<<nbPrep, 256, 0, stream>>>(x, xbf, cnt, colx, statsAcc, ticket);
    k_bucket_fill<<<nbE8, 256, 0, stream>>>(ei, cnt, colx);

    // ---- layer 1 ----
    k_gemm_fused<<<nbGemm, 512, 0, stream>>>(xbf, nullptr, nullptr, W1, cnt, h, nullptr,
                                             nullptr, nullptr, nullptr, nullptr);
    k_gcn_agg<<<NBPART, 256, 0, stream>>>(h, cnt, colx, aggP, part);
    k_bn_redfin<<<NBRED, 256, 0, stream>>>(part, statsAcc, ticket, stats, bn_g + 0 * Dd, bn_b + 0 * Dd);

    // ---- layer 2 ----
    k_gemm_fused<<<nbGemm, 512, 0, stream>>>(xbf, aggP, stats, W2, cnt, h, xcurP,
                                             nullptr, nullptr, nullptr, nullptr);
    k_gcn_agg<<<NBPART, 256, 0, stream>>>(h, cnt, colx, aggP, part);
    k_bn_redfin<<<NBRED, 256, 0, stream>>>(part, statsAcc, ticket, stats, bn_g + 1 * Dd, bn_b + 1 * Dd);

    // ---- layer 3 ----
    k_gemm_fused<<<nbGemm, 512, 0, stream>>>(xcurP, aggP, stats, W3, cnt, h, xcurP,
                                             nullptr, nullptr, nullptr, nullptr);
    k_gcn_agg<<<NBPART, 256, 0, stream>>>(h, cnt, colx, aggP, part);
    k_bn_redfin<<<NBRED, 256, 0, stream>>>(part, statsAcc, ticket, stats, bn_g + 2 * Dd, bn_b + 2 * Dd);

    // ---- GAT layer ----
    k_gemm_fused<<<nbGemm, 512, 0, stream>>>(xcurP, aggP, stats, Wa, nullptr, h, xcurP,
                                             a_src, a_dst, es, ed);
    k_gat_agg<<<NBPART, 256, 0, stream>>>(h, cnt, colx, es, ed, aggP, part);
    k_bn_redfin<<<NBRED, 256, 0, stream>>>(part, statsAcc, ticket, stats, bn_g + 3 * Dd, bn_b + 3 * Dd);

    // ---- mean pool fused with final BN-apply ----
    k_pool<<<Gg, 256, 0, stream>>>(aggP, stats, xcurP, batch, pooled);

    // ---- MLP head (MFMA bf16) ----
    k_mlp_mfma<<<(Gg / 64) * (NHIDc / 64), 256, 0, stream>>>(pooled, Wm1, bm1, m1, Gg, Dd, NHIDc, 1);
    k_mlp_mfma<<<(Gg / 64) * (NHIDc / 64), 256, 0, stream>>>(m1, Wm2, bm2, m2, Gg, NHIDc, NHIDc, 1);
    k_mlp_mfma<<<(Gg / 64) * (NHIDc / 64), 256, 0, stream>>>(m2, Wm3, bm3, m1, Gg, NHIDc, NHIDc, 1);
    k_mlp_mfma<<<(Gg / 64) * (NOUTc / 64), 256, 0, stream>>>(m1, Wm4, bm4, (float*)d_out, Gg, NHIDc, NOUTc, 0);
}

// Round 16
// 370.360 us; speedup vs baseline: 1.0973x; 1.0973x over previous
//
#include <hip/hip_runtime.h>
#include <stdint.h>

#define Nn   50000
#define Ee   800000
#define Dd   128
#define Gg   512
#define NHIDc 512
#define NOUTc 768
#define EPSf 1e-5f
#define CAP  64          // bucket capacity per node (Poisson(17), max deg ~46)
#define PRNG 6250        // node-range per XCD partition (Nn/8)
#define NBPART 12500     // agg blocks (block per 4 nodes) = #stat-partials
#define NB2    250       // stage-2 partials (NBPART/50)

// ---- workspace byte offsets ----
#define OFF_CNT    0ul            // N int (degree incl self-loop)
#define OFF_ES     200192ul       // N float
#define OFF_ED     400384ul       // N float
#define OFF_STATS  600576ul       // 256 float
#define OFF_POOLED 601600ul       // G*D float
#define OFF_M1     863744ul       // 512*512 float (also part2: 250*256 floats)
#define OFF_M2     1912320ul      // 512*512 float
#define OFF_COL    2960896ul      // N*64 int  (padded buckets)
#define OFF_H      15760896ul     // N*64 u32  (packed bf16x2)
#define OFF_AGG    28560896ul     // N*64 u32  (packed bf16x2)
#define OFF_XCUR   41360896ul     // N*64 u32  (packed bf16x2 residual stream)
#define OFF_PART   54160896ul     // NBPART*256 float = 12.8 MB stats partials
#define OFF_XBF    66960896ul     // N*64 u32  (packed bf16x2 input x)

#define BF_LO(u) __uint_as_float((u) << 16)
#define BF_HI(u) __uint_as_float((u) & 0xffff0000u)

typedef __attribute__((ext_vector_type(8))) short bf16x8;
typedef __attribute__((ext_vector_type(4))) float f32x4;

__device__ inline uint32_t bfpack(float x, float y) {
    uint32_t ux = __float_as_uint(x), uy = __float_as_uint(y);
    ux += 0x7fff + ((ux >> 16) & 1);   // RNE
    uy += 0x7fff + ((uy >> 16) & 1);
    return (ux >> 16) | (uy & 0xffff0000u);
}
__device__ inline short bf1(float x) {
    uint32_t u = __float_as_uint(x);
    u += 0x7fff + ((u >> 16) & 1);
    return (short)(u >> 16);
}
__device__ inline float wred16(float v) {
    v += __shfl_xor(v, 1); v += __shfl_xor(v, 2);
    v += __shfl_xor(v, 4); v += __shfl_xor(v, 8);
    return v;
}

// ---------------- prep: x->bf16 pack + bucket init (merged) ----------------
__global__ void k_prep(const float* __restrict__ x, uint32_t* __restrict__ xbf,
                       int* cnt, int* colx) {
    int i = blockIdx.x * 256 + threadIdx.x;   // Nn*16 = 800000 threads exactly
    {
        float4 a = reinterpret_cast<const float4*>(x)[2 * i];
        float4 b = reinterpret_cast<const float4*>(x)[2 * i + 1];
        uint32_t o[4] = {bfpack(a.x, a.y), bfpack(a.z, a.w),
                         bfpack(b.x, b.y), bfpack(b.z, b.w)};
        reinterpret_cast<uint4*>(xbf)[i] = *reinterpret_cast<uint4*>(o);
    }
    if (i < Nn) {
        cnt[i] = 1;                        // self-loop occupies slot 0
        colx[(size_t)i * CAP] = i;
    }
}

// XCD-partitioned fill: group g (blockIdx&7) handles dst in [g*PRNG,(g+1)*PRNG)
__global__ void k_bucket_fill(const int* __restrict__ ei, int* cnt, int* colx) {
    int grp = blockIdx.x & 7;
    int e = (blockIdx.x >> 3) * 256 + threadIdx.x;
    if (e >= Ee) return;
    int d = ei[Ee + e];
    if (d / PRNG != grp) return;
    int s = ei[e];
    int pos = atomicAdd(&cnt[d], 1);
    if (pos < CAP) colx[(size_t)d * CAP + pos] = s;
}

// ---------------- fused BN-apply + node GEMM (MFMA bf16) + optional GAT scores ----------------
#define WTP 136   // padded k-stride (bf16 elems); WTP/2 = 68 u32
__global__ __launch_bounds__(512) void k_gemm_fused(
        const uint32_t* __restrict__ XP, const uint32_t* __restrict__ AggP,
        const float* __restrict__ stats, const float* __restrict__ W,
        const int* __restrict__ cntP,
        uint32_t* __restrict__ Hout, uint32_t* __restrict__ XoutP,
        const float* __restrict__ a_src, const float* __restrict__ a_dst,
        float* __restrict__ esO, float* __restrict__ edO) {
    __shared__ short WT[128 * WTP];     // 34816 B : W^T bf16, WT[c*WTP+k]
    __shared__ short XT[8][16 * WTP];   // 34816 B : per-wave xnew slab (then H slab)
    __shared__ float isqL[128];

    int t = threadIdx.x;
    for (int i = t; i < 128 * 128; i += 512) {
        int k = i >> 7, c = i & 127;
        WT[c * WTP + k] = bf1(W[i]);
    }
    __syncthreads();

    int wave = t >> 6, lane = t & 63;
    int arow = lane & 15, kg = lane >> 4;
    int c4 = (lane * 4) & 63;           // phase-1: this lane's 4 u32 cols (8 features)
    int prow = lane >> 4;               // phase-1: row offset within 4-row group
    float scv[8], shv[8];
    if (stats) {
        #pragma unroll
        for (int j = 0; j < 8; ++j) {
            scv[j] = stats[2 * c4 + j];
            shv[j] = stats[128 + 2 * c4 + j];
        }
    }
    float asr[8], adr[8];
    if (esO) {
        #pragma unroll
        for (int jj = 0; jj < 8; ++jj) {
            asr[jj] = a_src[(lane & 15) * 8 + jj];
            adr[jj] = a_dst[(lane & 15) * 8 + jj];
        }
    }

    for (int tile = blockIdx.x * 128; tile < Nn; tile += gridDim.x * 128) {
        int rbase = tile + wave * 16;
        if (lane < 16) {
            int rg = rbase + lane;
            isqL[wave * 16 + lane] = (cntP && rg < Nn) ? rsqrtf((float)cntP[rg]) : 1.f;
        }
        // ---- phase 1: 4x uint4 coalesced loads -> BN+ReLU+residual -> bf16 slab ----
        uint32_t* xtw = reinterpret_cast<uint32_t*>(XT[wave]);
        #pragma unroll
        for (int b = 0; b < 4; ++b) {
            int row = b * 4 + prow;
            int rg = rbase + row;
            uint32_t xv[4] = {0u, 0u, 0u, 0u};
            if (rg < Nn) {
                *reinterpret_cast<uint4*>(xv) =
                    *reinterpret_cast<const uint4*>(&XP[(size_t)rg * 64 + c4]);
                if (AggP) {
                    uint32_t av[4];
                    *reinterpret_cast<uint4*>(av) =
                        *reinterpret_cast<const uint4*>(&AggP[(size_t)rg * 64 + c4]);
                    #pragma unroll
                    for (int q = 0; q < 4; ++q) {
                        float n0 = fmaxf(BF_LO(av[q]) * scv[2 * q] + shv[2 * q], 0.f) + BF_LO(xv[q]);
                        float n1 = fmaxf(BF_HI(av[q]) * scv[2 * q + 1] + shv[2 * q + 1], 0.f) + BF_HI(xv[q]);
                        xv[q] = bfpack(n0, n1);
                    }
                    *reinterpret_cast<uint4*>(&XoutP[(size_t)rg * 64 + c4]) =
                        *reinterpret_cast<uint4*>(xv);
                }
            }
            *reinterpret_cast<uint4*>(&xtw[row * (WTP / 2) + c4]) = *reinterpret_cast<uint4*>(xv);
        }
        // ---- phase 2: MFMA ----
        bf16x8 afr[4];
        #pragma unroll
        for (int kt = 0; kt < 4; ++kt)
            afr[kt] = *reinterpret_cast<bf16x8*>(&XT[wave][arow * WTP + kt * 32 + kg * 8]);
        float sR[4];
        #pragma unroll
        for (int rr = 0; rr < 4; ++rr) sR[rr] = isqL[wave * 16 + kg * 4 + rr];

        #pragma unroll
        for (int ct = 0; ct < 8; ++ct) {
            int c = ct * 16 + arow;
            f32x4 acc = {0.f, 0.f, 0.f, 0.f};
            #pragma unroll
            for (int kt = 0; kt < 4; ++kt) {
                bf16x8 b = *reinterpret_cast<bf16x8*>(&WT[c * WTP + kt * 32 + kg * 8]);
                acc = __builtin_amdgcn_mfma_f32_16x16x32_bf16(afr[kt], b, acc, 0, 0, 0);
            }
            #pragma unroll
            for (int rr = 0; rr < 4; ++rr)
                XT[wave][(kg * 4 + rr) * WTP + c] = bf1(acc[rr] * sR[rr]);
        }
        // ---- phase 3: coalesced copy-out + optional GAT scores ----
        #pragma unroll
        for (int p = 0; p < 4; ++p) {
            int rsl = p * 4 + kg;
            int rg = rbase + rsl;
            if (rg < Nn) {
                int chunk = lane & 15;
                bf16x8 vv = *reinterpret_cast<bf16x8*>(&XT[wave][rsl * WTP + chunk * 8]);
                *reinterpret_cast<bf16x8*>(reinterpret_cast<short*>(Hout) + (size_t)rg * 128 + chunk * 8) = vv;
                if (esO) {
                    float dsum = 0.f, ddum = 0.f;
                    #pragma unroll
                    for (int jj = 0; jj < 8; ++jj) {
                        float hv = __uint_as_float(((uint32_t)(unsigned short)vv[jj]) << 16);
                        dsum += hv * asr[jj];
                        ddum += hv * adr[jj];
                    }
                    dsum = wred16(dsum); ddum = wred16(ddum);
                    if ((lane & 15) == 0) { esO[rg] = dsum; edO[rg] = ddum; }
                }
            }
        }
    }
}

// ---------------- GCN aggregation + fused BN-stats partials ----------------
__global__ __launch_bounds__(256) void k_gcn_agg(const uint32_t* __restrict__ H,
                                                 const int* __restrict__ cnt,
                                                 const int* __restrict__ colx,
                                                 uint32_t* __restrict__ aggP,
                                                 float* __restrict__ part) {
    int wave = threadIdx.x >> 6, lane = threadIdx.x & 63;
    int half = lane >> 5, fl = lane & 31;
    int nid = blockIdx.x * 4 + wave;
    const uint2* H2 = reinterpret_cast<const uint2*>(H);

    int degF = cnt[nid];
    int deg = degF > CAP ? CAP : degF;
    size_t cb = (size_t)nid * CAP;
    int m = (deg - half + 1) >> 1;
    float f0a = 0.f, f1a = 0.f, f2a = 0.f, f3a = 0.f;
    float f0b = 0.f, f1b = 0.f, f2b = 0.f, f3b = 0.f;
    float f0c = 0.f, f1c = 0.f, f2c = 0.f, f3c = 0.f;
    float f0d = 0.f, f1d = 0.f, f2d = 0.f, f3d = 0.f;
    int k = 0;
    for (; k + 3 < m; k += 4) {
        int s0 = colx[cb + half + 2 * k];
        int s1 = colx[cb + half + 2 * k + 2];
        int s2 = colx[cb + half + 2 * k + 4];
        int s3 = colx[cb + half + 2 * k + 6];
        uint2 u0 = H2[(size_t)s0 * 32 + fl];
        uint2 u1 = H2[(size_t)s1 * 32 + fl];
        uint2 u2 = H2[(size_t)s2 * 32 + fl];
        uint2 u3 = H2[(size_t)s3 * 32 + fl];
        f0a += BF_LO(u0.x); f1a += BF_HI(u0.x); f2a += BF_LO(u0.y); f3a += BF_HI(u0.y);
        f0b += BF_LO(u1.x); f1b += BF_HI(u1.x); f2b += BF_LO(u1.y); f3b += BF_HI(u1.y);
        f0c += BF_LO(u2.x); f1c += BF_HI(u2.x); f2c += BF_LO(u2.y); f3c += BF_HI(u2.y);
        f0d += BF_LO(u3.x); f1d += BF_HI(u3.x); f2d += BF_LO(u3.y); f3d += BF_HI(u3.y);
    }
    for (; k < m; ++k) {
        int s0 = colx[cb + half + 2 * k];
        uint2 u0 = H2[(size_t)s0 * 32 + fl];
        f0a += BF_LO(u0.x); f1a += BF_HI(u0.x); f2a += BF_LO(u0.y); f3a += BF_HI(u0.y);
    }
    float f0 = (f0a + f0b) + (f0c + f0d);
    float f1 = (f1a + f1b) + (f1c + f1d);
    float f2 = (f2a + f2b) + (f2c + f2d);
    float f3 = (f3a + f3b) + (f3c + f3d);
    f0 += __shfl_xor(f0, 32); f1 += __shfl_xor(f1, 32);
    f2 += __shfl_xor(f2, 32); f3 += __shfl_xor(f3, 32);

    float o0 = 0.f, o1 = 0.f, o2 = 0.f, o3 = 0.f;
    if (half == 0) {
        float wd = rsqrtf((float)degF);
        o0 = f0 * wd; o1 = f1 * wd; o2 = f2 * wd; o3 = f3 * wd;
        uint2 o;
        o.x = bfpack(o0, o1);
        o.y = bfpack(o2, o3);
        reinterpret_cast<uint2*>(aggP)[(size_t)nid * 32 + fl] = o;
    }
    __shared__ float SS[4][128];
    __shared__ float QQ[4][128];
    if (half == 0) {
        SS[wave][4 * fl + 0] = o0; QQ[wave][4 * fl + 0] = o0 * o0;
        SS[wave][4 * fl + 1] = o1; QQ[wave][4 * fl + 1] = o1 * o1;
        SS[wave][4 * fl + 2] = o2; QQ[wave][4 * fl + 2] = o2 * o2;
        SS[wave][4 * fl + 3] = o3; QQ[wave][4 * fl + 3] = o3 * o3;
    }
    __syncthreads();
    int t = threadIdx.x;
    if (t < 128) {
        part[blockIdx.x * 256 + t]       = (SS[0][t] + SS[1][t]) + (SS[2][t] + SS[3][t]);
        part[blockIdx.x * 256 + 128 + t] = (QQ[0][t] + QQ[1][t]) + (QQ[2][t] + QQ[3][t]);
    }
}

// ---------------- GAT aggregation + fused BN-stats partials ----------------
__global__ __launch_bounds__(256) void k_gat_agg(const uint32_t* __restrict__ H,
                                                 const int* __restrict__ cnt,
                                                 const int* __restrict__ colx,
                                                 const float* __restrict__ es,
                                                 const float* __restrict__ ed,
                                                 uint32_t* __restrict__ aggP,
                                                 float* __restrict__ part) {
    int wave = threadIdx.x >> 6, lane = threadIdx.x & 63;
    int half = lane >> 5, fl = lane & 31;
    int nid = blockIdx.x * 4 + wave;
    const uint2* H2 = reinterpret_cast<const uint2*>(H);

    int degF = cnt[nid];
    int deg = degF > CAP ? CAP : degF;
    size_t cb = (size_t)nid * CAP;
    float edd = ed[nid];
    int m = (deg - half + 1) >> 1;
    float f0a = 0.f, f1a = 0.f, f2a = 0.f, f3a = 0.f, dena = 0.f;
    float f0b = 0.f, f1b = 0.f, f2b = 0.f, f3b = 0.f, denb = 0.f;
    float f0c = 0.f, f1c = 0.f, f2c = 0.f, f3c = 0.f, denc = 0.f;
    float f0d = 0.f, f1d = 0.f, f2d = 0.f, f3d = 0.f, dend = 0.f;
    int k = 0;
    for (; k + 3 < m; k += 4) {
        int s0 = colx[cb + half + 2 * k];
        int s1 = colx[cb + half + 2 * k + 2];
        int s2 = colx[cb + half + 2 * k + 4];
        int s3 = colx[cb + half + 2 * k + 6];
        float e0 = es[s0] + edd, e1 = es[s1] + edd;
        float e2 = es[s2] + edd, e3 = es[s3] + edd;
        e0 = (e0 < 0.f) ? 0.2f * e0 : e0;
        e1 = (e1 < 0.f) ? 0.2f * e1 : e1;
        e2 = (e2 < 0.f) ? 0.2f * e2 : e2;
        e3 = (e3 < 0.f) ? 0.2f * e3 : e3;
        float w0 = __expf(e0), w1 = __expf(e1), w2 = __expf(e2), w3 = __expf(e3);
        uint2 u0 = H2[(size_t)s0 * 32 + fl];
        uint2 u1 = H2[(size_t)s1 * 32 + fl];
        uint2 u2 = H2[(size_t)s2 * 32 + fl];
        uint2 u3 = H2[(size_t)s3 * 32 + fl];
        f0a += w0 * BF_LO(u0.x); f1a += w0 * BF_HI(u0.x);
        f2a += w0 * BF_LO(u0.y); f3a += w0 * BF_HI(u0.y); dena += w0;
        f0b += w1 * BF_LO(u1.x); f1b += w1 * BF_HI(u1.x);
        f2b += w1 * BF_LO(u1.y); f3b += w1 * BF_HI(u1.y); denb += w1;
        f0c += w2 * BF_LO(u2.x); f1c += w2 * BF_HI(u2.x);
        f2c += w2 * BF_LO(u2.y); f3c += w2 * BF_HI(u2.y); denc += w2;
        f0d += w3 * BF_LO(u3.x); f1d += w3 * BF_HI(u3.x);
        f2d += w3 * BF_LO(u3.y); f3d += w3 * BF_HI(u3.y); dend += w3;
    }
    for (; k < m; ++k) {
        int s0 = colx[cb + half + 2 * k];
        float e0 = es[s0] + edd;
        e0 = (e0 < 0.f) ? 0.2f * e0 : e0;
        float w0 = __expf(e0);
        uint2 u0 = H2[(size_t)s0 * 32 + fl];
        f0a += w0 * BF_LO(u0.x); f1a += w0 * BF_HI(u0.x);
        f2a += w0 * BF_LO(u0.y); f3a += w0 * BF_HI(u0.y); dena += w0;
    }
    float f0 = (f0a + f0b) + (f0c + f0d);
    float f1 = (f1a + f1b) + (f1c + f1d);
    float f2 = (f2a + f2b) + (f2c + f2d);
    float f3 = (f3a + f3b) + (f3c + f3d);
    float den = (dena + denb) + (denc + dend);
    f0 += __shfl_xor(f0, 32); f1 += __shfl_xor(f1, 32);
    f2 += __shfl_xor(f2, 32); f3 += __shfl_xor(f3, 32);
    den += __shfl_xor(den, 32);

    float o0 = 0.f, o1 = 0.f, o2 = 0.f, o3 = 0.f;
    if (half == 0) {
        float inv = 1.f / den;
        o0 = f0 * inv; o1 = f1 * inv; o2 = f2 * inv; o3 = f3 * inv;
        uint2 o;
        o.x = bfpack(o0, o1);
        o.y = bfpack(o2, o3);
        reinterpret_cast<uint2*>(aggP)[(size_t)nid * 32 + fl] = o;
    }
    __shared__ float SS[4][128];
    __shared__ float QQ[4][128];
    if (half == 0) {
        SS[wave][4 * fl + 0] = o0; QQ[wave][4 * fl + 0] = o0 * o0;
        SS[wave][4 * fl + 1] = o1; QQ[wave][4 * fl + 1] = o1 * o1;
        SS[wave][4 * fl + 2] = o2; QQ[wave][4 * fl + 2] = o2 * o2;
        SS[wave][4 * fl + 3] = o3; QQ[wave][4 * fl + 3] = o3 * o3;
    }
    __syncthreads();
    int t = threadIdx.x;
    if (t < 128) {
        part[blockIdx.x * 256 + t]       = (SS[0][t] + SS[1][t]) + (SS[2][t] + SS[3][t]);
        part[blockIdx.x * 256 + 128 + t] = (QQ[0][t] + QQ[1][t]) + (QQ[2][t] + QQ[3][t]);
    }
}

// ---------------- BN reduce stage 1: coalesced row sums, 50 rows/block ----------------
__global__ __launch_bounds__(256) void k_bn_red1(const float* __restrict__ part,
                                                 float* __restrict__ part2) {
    int t = threadIdx.x;
    int r0 = blockIdx.x * 50;
    float acc = 0.f;
    #pragma unroll 5
    for (int r = r0; r < r0 + 50; ++r) acc += part[(size_t)r * 256 + t];
    part2[blockIdx.x * 256 + t] = acc;
}

// ---------------- BN finalize: block per feature over NB2 rows ----------------
__global__ __launch_bounds__(256) void k_bn_final(const float* __restrict__ part2, float* stats,
                                                  const float* __restrict__ gamma,
                                                  const float* __restrict__ beta) {
    int f = blockIdx.x;          // 0..127
    int t = threadIdx.x;
    float s = 0.f, q = 0.f;
    if (t < NB2) {
        s = part2[t * 256 + f];
        q = part2[t * 256 + 128 + f];
    }
    #pragma unroll
    for (int o = 32; o > 0; o >>= 1) { s += __shfl_xor(s, o); q += __shfl_xor(q, o); }
    __shared__ float rs[4], rq[4];
    if ((t & 63) == 0) { rs[t >> 6] = s; rq[t >> 6] = q; }
    __syncthreads();
    if (t == 0) {
        float S = (rs[0] + rs[1]) + (rs[2] + rs[3]);
        float Q = (rq[0] + rq[1]) + (rq[2] + rq[3]);
        const float invN = 1.f / (float)Nn;
        float mean = S * invN;
        float var = Q * invN - mean * mean;
        float scv = rsqrtf(var + EPSf) * gamma[f];
        stats[f] = scv;
        stats[128 + f] = beta[f] - mean * scv;
    }
}

// ---------------- mean pool, fused with final BN-apply (packed inputs) ----------------
__global__ __launch_bounds__(256) void k_pool(const uint32_t* __restrict__ AP,
                                              const float* __restrict__ stats,
                                              const uint32_t* __restrict__ XcP,
                                              const int* __restrict__ batch,
                                              float* __restrict__ pooled) {
    int g = blockIdx.x;
    int lo = 0, hi = Nn;
    while (lo < hi) { int mid = (lo + hi) >> 1; if (batch[mid] < g) lo = mid + 1; else hi = mid; }
    int start = lo;
    lo = start; hi = Nn;
    while (lo < hi) { int mid = (lo + hi) >> 1; if (batch[mid] < g + 1) lo = mid + 1; else hi = mid; }
    int end = lo;

    int f = threadIdx.x & 127, rg = threadIdx.x >> 7;
    float sc = stats[f], sh = stats[128 + f];
    float s = 0.f;
    for (int r = start + rg; r < end; r += 2) {
        uint32_t u = AP[(size_t)r * 64 + (f >> 1)];
        uint32_t ux = XcP[(size_t)r * 64 + (f >> 1)];
        float a  = (f & 1) ? BF_HI(u)  : BF_LO(u);
        float xv = (f & 1) ? BF_HI(ux) : BF_LO(ux);
        s += fmaxf(a * sc + sh, 0.f) + xv;
    }
    __shared__ float red[256];
    red[threadIdx.x] = s; __syncthreads();
    if (threadIdx.x < 128) {
        float tot = red[threadIdx.x] + red[threadIdx.x + 128];
        float cntg = (float)(end - start);
        pooled[g * Dd + threadIdx.x] = (cntg > 0.f) ? tot / cntg : 0.f;
    }
}

// ---------------- MLP GEMM: LDS-tiled fp32, 32x64 tile per 256-thr block ----------------
__global__ __launch_bounds__(256) void k_mlp32(const float* __restrict__ A,
                                               const float* __restrict__ B,
                                               const float* __restrict__ bias,
                                               float* __restrict__ C,
                                               int M, int K, int Nc, int do_relu) {
    __shared__ float Ast[64][36];
    __shared__ float Bs[64][68];

    int nbx = Nc >> 6;
    int by = blockIdx.x / nbx, bx = blockIdx.x - by * nbx;
    int r0 = by * 32, c0 = bx * 64;
    int t = threadIdx.x;
    int tc = t & 31, tr = t >> 5;

    float2 acc0 = {0, 0}, acc1 = {0, 0}, acc2 = {0, 0}, acc3 = {0, 0};

    int sar = t >> 3, sak = (t & 7) * 8;
    int sbk = t >> 2, sbc = (t & 3) * 16;

    for (int kc = 0; kc < K; kc += 64) {
        {
            const float* ap = A + (size_t)(r0 + sar) * K + kc + sak;
            float4 v0 = *reinterpret_cast<const float4*>(ap);
            float4 v1 = *reinterpret_cast<const float4*>(ap + 4);
            Ast[sak + 0][sar] = v0.x; Ast[sak + 1][sar] = v0.y;
            Ast[sak + 2][sar] = v0.z; Ast[sak + 3][sar] = v0.w;
            Ast[sak + 4][sar] = v1.x; Ast[sak + 5][sar] = v1.y;
            Ast[sak + 6][sar] = v1.z; Ast[sak + 7][sar] = v1.w;
        }
        {
            const float* bp = B + (size_t)(kc + sbk) * Nc + c0 + sbc;
            float4 w0 = *reinterpret_cast<const float4*>(bp);
            float4 w1 = *reinterpret_cast<const float4*>(bp + 4);
            float4 w2 = *reinterpret_cast<const float4*>(bp + 8);
            float4 w3 = *reinterpret_cast<const float4*>(bp + 12);
            *reinterpret_cast<float4*>(&Bs[sbk][sbc]) = w0;
            *reinterpret_cast<float4*>(&Bs[sbk][sbc + 4]) = w1;
            *reinterpret_cast<float4*>(&Bs[sbk][sbc + 8]) = w2;
            *reinterpret_cast<float4*>(&Bs[sbk][sbc + 12]) = w3;
        }
        __syncthreads();
        #pragma unroll 8
        for (int k = 0; k < 64; ++k) {
            float4 a = *reinterpret_cast<float4*>(&Ast[k][tr * 4]);
            float2 b = *reinterpret_cast<float2*>(&Bs[k][tc * 2]);
            acc0.x += a.x * b.x; acc0.y += a.x * b.y;
            acc1.x += a.y * b.x; acc1.y += a.y * b.y;
            acc2.x += a.z * b.x; acc2.y += a.z * b.y;
            acc3.x += a.w * b.x; acc3.y += a.w * b.y;
        }
        __syncthreads();
    }

    float b0 = bias[c0 + tc * 2], b1 = bias[c0 + tc * 2 + 1];
    float2 r[4] = {{acc0.x + b0, acc0.y + b1}, {acc1.x + b0, acc1.y + b1},
                   {acc2.x + b0, acc2.y + b1}, {acc3.x + b0, acc3.y + b1}};
    if (do_relu) {
        #pragma unroll
        for (int i = 0; i < 4; ++i) {
            r[i].x = fmaxf(r[i].x, 0.f); r[i].y = fmaxf(r[i].y, 0.f);
        }
    }
    #pragma unroll
    for (int i = 0; i < 4; ++i)
        *reinterpret_cast<float2*>(C + (size_t)(r0 + tr * 4 + i) * Nc + c0 + tc * 2) = r[i];
}

extern "C" void kernel_launch(void* const* d_in, const int* in_sizes, int n_in,
                              void* d_out, int out_size, void* d_ws, size_t ws_size,
                              hipStream_t stream) {
    const float* x       = (const float*)d_in[0];
    const int*   ei      = (const int*)d_in[1];
    const int*   batch   = (const int*)d_in[2];
    const float* W1      = (const float*)d_in[3];
    const float* W2      = (const float*)d_in[5];
    const float* W3      = (const float*)d_in[7];
    const float* Wa      = (const float*)d_in[9];
    const float* a_src   = (const float*)d_in[11];
    const float* a_dst   = (const float*)d_in[12];
    const float* bn_g    = (const float*)d_in[13];
    const float* bn_b    = (const float*)d_in[14];
    const float* Wm1     = (const float*)d_in[15];
    const float* bm1     = (const float*)d_in[16];
    const float* Wm2     = (const float*)d_in[17];
    const float* bm2     = (const float*)d_in[18];
    const float* Wm3     = (const float*)d_in[19];
    const float* bm3     = (const float*)d_in[20];
    const float* Wm4     = (const float*)d_in[21];
    const float* bm4     = (const float*)d_in[22];

    char* ws = (char*)d_ws;
    int*      cnt    = (int*)(ws + OFF_CNT);
    float*    es     = (float*)(ws + OFF_ES);
    float*    ed     = (float*)(ws + OFF_ED);
    float*    stats  = (float*)(ws + OFF_STATS);
    float*    pooled = (float*)(ws + OFF_POOLED);
    float*    m1     = (float*)(ws + OFF_M1);
    float*    m2     = (float*)(ws + OFF_M2);
    int*      colx   = (int*)(ws + OFF_COL);
    uint32_t* h      = (uint32_t*)(ws + OFF_H);
    uint32_t* aggP   = (uint32_t*)(ws + OFF_AGG);
    uint32_t* xcurP  = (uint32_t*)(ws + OFF_XCUR);
    float*    part   = (float*)(ws + OFF_PART);  // NBPART*256 floats = 12.8 MB
    uint32_t* xbf    = (uint32_t*)(ws + OFF_XBF);
    float*    part2  = m1;                       // NB2*256 floats = 256 KB

    const int nbE8  = ((Ee + 255) / 256) * 8;    // 25000 partitioned blocks
    const int nbGemm = (Nn + 127) / 128;         // 391 tiles of 128 rows (512 thr)
    const int nbPrep = (Nn * 16 + 255) / 256;    // 3125 (exact for x pack)

    // ---- prep (x pack + bucket init) + bucket fill ----
    k_prep<<<nbPrep, 256, 0, stream>>>(x, xbf, cnt, colx);
    k_bucket_fill<<<nbE8, 256, 0, stream>>>(ei, cnt, colx);

    // ---- layer 1 ----
    k_gemm_fused<<<nbGemm, 512, 0, stream>>>(xbf, nullptr, nullptr, W1, cnt, h, nullptr,
                                             nullptr, nullptr, nullptr, nullptr);
    k_gcn_agg<<<NBPART, 256, 0, stream>>>(h, cnt, colx, aggP, part);
    k_bn_red1<<<NB2, 256, 0, stream>>>(part, part2);
    k_bn_final<<<128, 256, 0, stream>>>(part2, stats, bn_g + 0 * Dd, bn_b + 0 * Dd);

    // ---- layer 2 ----
    k_gemm_fused<<<nbGemm, 512, 0, stream>>>(xbf, aggP, stats, W2, cnt, h, xcurP,
                                             nullptr, nullptr, nullptr, nullptr);
    k_gcn_agg<<<NBPART, 256, 0, stream>>>(h, cnt, colx, aggP, part);
    k_bn_red1<<<NB2, 256, 0, stream>>>(part, part2);
    k_bn_final<<<128, 256, 0, stream>>>(part2, stats, bn_g + 1 * Dd, bn_b + 1 * Dd);

    // ---- layer 3 ----
    k_gemm_fused<<<nbGemm, 512, 0, stream>>>(xcurP, aggP, stats, W3, cnt, h, xcurP,
                                             nullptr, nullptr, nullptr, nullptr);
    k_gcn_agg<<<NBPART, 256, 0, stream>>>(h, cnt, colx, aggP, part);
    k_bn_red1<<<NB2, 256, 0, stream>>>(part, part2);
    k_bn_final<<<128, 256, 0, stream>>>(part2, stats, bn_g + 2 * Dd, bn_b + 2 * Dd);

    // ---- GAT layer ----
    k_gemm_fused<<<nbGemm, 512, 0, stream>>>(xcurP, aggP, stats, Wa, nullptr, h, xcurP,
                                             a_src, a_dst, es, ed);
    k_gat_agg<<<NBPART, 256, 0, stream>>>(h, cnt, colx, es, ed, aggP, part);
    k_bn_red1<<<NB2, 256, 0, stream>>>(part, part2);
    k_bn_final<<<128, 256, 0, stream>>>(part2, stats, bn_g + 3 * Dd, bn_b + 3 * Dd);

    // ---- mean pool fused with final BN-apply ----
    k_pool<<<Gg, 256, 0, stream>>>(aggP, stats, xcurP, batch, pooled);

    // ---- MLP head ----
    k_mlp32<<<(Gg / 32) * (NHIDc / 64), 256, 0, stream>>>(pooled, Wm1, bm1, m1, Gg, Dd, NHIDc, 1);
    k_mlp32<<<(Gg / 32) * (NHIDc / 64), 256, 0, stream>>>(m1, Wm2, bm2, m2, Gg, NHIDc, NHIDc, 1);
    k_mlp32<<<(Gg / 32) * (NHIDc / 64), 256, 0, stream>>>(m2, Wm3, bm3, m1, Gg, NHIDc, NHIDc, 1);
    k_mlp32<<<(Gg / 32) * (NOUTc / 64), 256, 0, stream>>>(m1, Wm4, bm4, (float*)d_out, Gg, NHIDc, NOUTc, 0);
}